// Round 2
// 386.816 us; speedup vs baseline: 1.1192x; 1.1192x over previous
//
#include <hip/hip_runtime.h>
#include <math.h>

#define F_IN 128
#define TDIM 64
#define NGRAPH 256

typedef __attribute__((ext_vector_type(8))) short short8;
typedef __attribute__((ext_vector_type(4))) float f32x4;
typedef __attribute__((ext_vector_type(2))) __fp16 fp16x2;

__device__ __forceinline__ float gelu_f(float x) {
    float x3 = x * x * x;
    return 0.5f * x * (1.0f + tanhf(0.7978845608028654f * (x + 0.044715f * x3)));
}

__device__ __forceinline__ unsigned short bf16_of(float x) {
    unsigned u = __float_as_uint(x);
    return (unsigned short)((u + 0x7fffu + ((u >> 16) & 1u)) >> 16);
}
__device__ __forceinline__ float f_of(unsigned short h) {
    return __uint_as_float(((unsigned)h) << 16);
}
__device__ __forceinline__ unsigned bf16pair(float a, float b) {
    return (unsigned)bf16_of(a) | ((unsigned)bf16_of(b) << 16);
}
__device__ __forceinline__ float2 bf16unpack(unsigned u) {
    float2 r;
    r.x = __uint_as_float(u << 16);
    r.y = __uint_as_float(u & 0xffff0000u);
    return r;
}

// fp16 pair pack/unpack (intermediate xl buffers are fp16: more mantissa than bf16,
// and enables v_fma_mix_f32 in the aggregation inner loop -> no unpack VALU)
__device__ __forceinline__ unsigned pkf16(float a, float b) {
    fp16x2 h = __builtin_amdgcn_cvt_pkrtz(a, b);
    return __builtin_bit_cast(unsigned, h);
}
__device__ __forceinline__ float2 f16unpack(unsigned u) {
    fp16x2 h = __builtin_bit_cast(fp16x2, u);
    float2 r;
    r.x = (float)h[0];
    r.y = (float)h[1];
    return r;
}

// acc += nw * f16lo(pk), acc2 += nw * f16hi(pk) -- single VALU op each, no unpack
__device__ __forceinline__ void fmix2(float& ax, float& ay, unsigned pk, float nw) {
    asm("v_fma_mix_f32 %0, %1, %2, %0 op_sel:[0,0,0] op_sel_hi:[1,0,0]"
        : "+v"(ax)
        : "v"(pk), "v"(nw));
    asm("v_fma_mix_f32 %0, %1, %2, %0 op_sel:[1,0,0] op_sel_hi:[1,0,0]"
        : "+v"(ay)
        : "v"(pk), "v"(nw));
}

// ---------------- edge build: fixed-stride bucket binning (packed records) ----------------

#define BIN_CH 4096
#define MAXNB 512
#define CAP 6144

__global__ __launch_bounds__(256) void zero_kernel(float* __restrict__ psum,
                                                   float* __restrict__ pcnt,
                                                   int* __restrict__ bucket_cnt) {
    int i = blockIdx.x * 256 + threadIdx.x;
    if (i < NGRAPH * TDIM) psum[i] = 0.f;
    if (i < NGRAPH) pcnt[i] = 0.f;
    if (i < MAXNB) bucket_cnt[i] = 0;
}

__global__ __launch_bounds__(256) void binC_kernel(const int* __restrict__ src,
                                                   const int* __restrict__ dst,
                                                   int* __restrict__ bucket_cnt,
                                                   unsigned* __restrict__ tmp, int E, int NB) {
    __shared__ int hist[MAXNB];
    __shared__ int hbase[MAXNB];
    __shared__ int hcur[MAXNB];
    int tid = threadIdx.x;
    int base = blockIdx.x * BIN_CH;
    int end = base + BIN_CH;
    if (end > E) end = E;
    for (int i = tid; i < NB; i += 256) hist[i] = 0;
    __syncthreads();
    for (int e = base + tid; e < end; e += 256) atomicAdd(&hist[dst[e] >> 8], 1);
    __syncthreads();
    for (int i = tid; i < NB; i += 256) {
        int c = hist[i];
        hbase[i] = (c > 0) ? atomicAdd(&bucket_cnt[i], c) : 0;
        hcur[i] = 0;
    }
    __syncthreads();
    for (int e = base + tid; e < end; e += 256) {
        int d = dst[e];
        int b = d >> 8;
        int p = atomicAdd(&hcur[b], 1);
        int slot = hbase[b] + p;
        if (slot < CAP)
            tmp[(size_t)b * CAP + slot] = (unsigned)src[e] | ((unsigned)(d & 255) << 24);
    }
}

// merged: block 0 = PARALLEL bucket scan; blocks >=1 = weight hi/lo split
__global__ __launch_bounds__(256) void scan_wconv_kernel(const int* __restrict__ bucket_cnt,
                                                         int* __restrict__ bbase,
                                                         int* __restrict__ row_off, int NB,
                                                         int N, const float* __restrict__ W0,
                                                         const float* __restrict__ W1,
                                                         const float* __restrict__ W2,
                                                         unsigned short* __restrict__ hi0,
                                                         unsigned short* __restrict__ lo0,
                                                         unsigned short* __restrict__ hi1,
                                                         unsigned short* __restrict__ lo1,
                                                         unsigned short* __restrict__ hi2,
                                                         unsigned short* __restrict__ lo2) {
    if (blockIdx.x == 0) {
        // parallel exclusive scan over NB (<= MAXNB = 512) clipped bucket counts
        __shared__ int sh[256];
        int tid = threadIdx.x;
        int i0 = tid * 2;
        int v0 = 0, v1 = 0;
        if (i0 < NB) {
            v0 = bucket_cnt[i0];
            v0 = v0 < CAP ? v0 : CAP;
        }
        if (i0 + 1 < NB) {
            v1 = bucket_cnt[i0 + 1];
            v1 = v1 < CAP ? v1 : CAP;
        }
        int s = v0 + v1;
        sh[tid] = s;
        __syncthreads();
        for (int off = 1; off < 256; off <<= 1) {
            int x = (tid >= off) ? sh[tid - off] : 0;
            __syncthreads();
            sh[tid] += x;
            __syncthreads();
        }
        int excl = sh[tid] - s;
        if (i0 < NB) bbase[i0] = excl;
        if (i0 + 1 < NB) bbase[i0 + 1] = excl + v0;
        if (tid == 255) row_off[N] = sh[255];
        return;
    }
    int idx = (blockIdx.x - 1) * 256 + threadIdx.x;
    const float* W;
    unsigned short *whi, *wlo;
    int local, FOUT;
    if (idx < 16384) {
        W = W0; whi = hi0; wlo = lo0; local = idx; FOUT = 128;
    } else if (idx < 32768) {
        W = W1; whi = hi1; wlo = lo1; local = idx - 16384; FOUT = 128;
    } else if (idx < 40960) {
        W = W2; whi = hi2; wlo = lo2; local = idx - 32768; FOUT = 64;
    } else {
        return;
    }
    int k = local / FOUT;
    int n = local % FOUT;
    float w = W[local];
    unsigned short h = bf16_of(w);
    whi[(size_t)n * 128 + k] = h;
    wlo[(size_t)n * 128 + k] = bf16_of(w - f_of(h));
}

__global__ __launch_bounds__(256) void binDcount_kernel(const unsigned* __restrict__ tmp,
                                                        const int* __restrict__ bucket_cnt,
                                                        const int* __restrict__ bbase,
                                                        int* __restrict__ row_off,
                                                        float* __restrict__ isq,
                                                        float* __restrict__ dinv, int N) {
    __shared__ int lcnt[256];
    __shared__ int sh[256];
    int b = blockIdx.x;
    int tid = threadIdx.x;
    int cntb = bucket_cnt[b];
    if (cntb > CAP) cntb = CAP;
    lcnt[tid] = 0;
    __syncthreads();
    const unsigned* tb = tmp + (size_t)b * CAP;
    for (int e = tid; e < cntb; e += 256) atomicAdd(&lcnt[tb[e] >> 24], 1);
    __syncthreads();
    int own = lcnt[tid];
    sh[tid] = own;
    __syncthreads();
    for (int off = 1; off < 256; off <<= 1) {
        int x = (tid >= off) ? sh[tid - off] : 0;
        __syncthreads();
        sh[tid] += x;
        __syncthreads();
    }
    int excl = sh[tid] - own;
    int node = (b << 8) + tid;
    if (node < N) {
        row_off[node] = bbase[b] + excl;
        float d = (float)own + 1.0f;
        isq[node] = rsqrtf(d);
        dinv[node] = 1.0f / d;
    }
}

__global__ __launch_bounds__(256) void binDscatter_kernel(const unsigned* __restrict__ tmp,
                                                          const int* __restrict__ bucket_cnt,
                                                          const int* __restrict__ row_off,
                                                          const float* __restrict__ isq,
                                                          uint2* __restrict__ edges, int N) {
    __shared__ int lcur[256];
    __shared__ float lisq[256];
    int b = blockIdx.x;
    int node0 = b << 8;
    int tid = threadIdx.x;
    lcur[tid] = 0;
    int nd = node0 + tid;
    lisq[tid] = (nd < N) ? isq[nd] : 0.f;
    __syncthreads();
    int cntb = bucket_cnt[b];
    if (cntb > CAP) cntb = CAP;
    const unsigned* tb = tmp + (size_t)b * CAP;
    for (int e = tid; e < cntb; e += 256) {
        unsigned rec = tb[e];
        int dl = (int)(rec >> 24);
        unsigned s = rec & 0xFFFFFFu;
        int p = atomicAdd(&lcur[dl], 1);
        float nrm = isq[s] * lisq[dl];
        edges[(size_t)row_off[node0 + dl] + p] = make_uint2(s, __float_as_uint(nrm));
    }
}

// ---------------- MFMA GEMM layer0 (fp32 X, split-bf16 W, 3 MFMA, 4 M-tiles/wave) ----------------
// 256-row blocks: B-frag LDS reads amortized over 4 M-tiles (LDS-BW balance).
// Output packed FP16 (consumed by aggregation via v_fma_mix).

#define LROW 136  // LDS row stride in shorts (272 B)

__global__ __launch_bounds__(256) void gemm_f32_kernel(const float* __restrict__ X,
                                                       const unsigned short* __restrict__ whiT,
                                                       const unsigned short* __restrict__ wloT,
                                                       unsigned* __restrict__ Yb, int nrows) {
    constexpr int FOUT = 128;
    constexpr int NT = FOUT / 16;
    __shared__ short lds[2 * FOUT * LROW];
    short* shi = lds;
    short* slo = lds + FOUT * LROW;

    for (int c = threadIdx.x; c < FOUT * 16; c += 256) {
        int n = c >> 4, r = c & 15;
        *(short8*)(shi + n * LROW + r * 8) = *(const short8*)(whiT + (size_t)n * 128 + r * 8);
        *(short8*)(slo + n * LROW + r * 8) = *(const short8*)(wloT + (size_t)n * 128 + r * 8);
    }
    __syncthreads();

    int lane = threadIdx.x & 63;
    int wave = threadIdx.x >> 6;
    int quad = lane >> 4;
    int l16 = lane & 15;
    int rowBase = blockIdx.x * 256 + wave * 64;

    f32x4 acc[4][NT];
#pragma unroll
    for (int m = 0; m < 4; ++m)
#pragma unroll
        for (int t = 0; t < NT; ++t) acc[m][t] = (f32x4){0.f, 0.f, 0.f, 0.f};

    const float* xr[4];
    bool ok[4];
#pragma unroll
    for (int m = 0; m < 4; ++m) {
        int arow = rowBase + m * 16 + l16;
        ok[m] = arow < nrows;
        xr[m] = X + (size_t)arow * 128;
    }

#pragma unroll
    for (int k0 = 0; k0 < 128; k0 += 32) {
        short8 ahi[4], alo[4];
#pragma unroll
        for (int m = 0; m < 4; ++m) {
            float xv[8];
            if (ok[m]) {
                float4 v0 = *(const float4*)(xr[m] + k0 + quad * 8);
                float4 v1 = *(const float4*)(xr[m] + k0 + quad * 8 + 4);
                xv[0] = v0.x; xv[1] = v0.y; xv[2] = v0.z; xv[3] = v0.w;
                xv[4] = v1.x; xv[5] = v1.y; xv[6] = v1.z; xv[7] = v1.w;
            } else {
#pragma unroll
                for (int j = 0; j < 8; ++j) xv[j] = 0.f;
            }
#pragma unroll
            for (int j = 0; j < 8; ++j) {
                unsigned short h = bf16_of(xv[j]);
                ahi[m][j] = (short)h;
                alo[m][j] = (short)bf16_of(xv[j] - f_of(h));
            }
        }
#pragma unroll
        for (int t = 0; t < NT; ++t) {
            int off = (t * 16 + l16) * LROW + k0 + quad * 8;
            short8 bhi = *(const short8*)(shi + off);
            short8 blo = *(const short8*)(slo + off);
#pragma unroll
            for (int m = 0; m < 4; ++m) {
                acc[m][t] = __builtin_amdgcn_mfma_f32_16x16x32_bf16(ahi[m], bhi, acc[m][t], 0, 0, 0);
                acc[m][t] = __builtin_amdgcn_mfma_f32_16x16x32_bf16(alo[m], bhi, acc[m][t], 0, 0, 0);
                acc[m][t] = __builtin_amdgcn_mfma_f32_16x16x32_bf16(ahi[m], blo, acc[m][t], 0, 0, 0);
            }
        }
    }

#pragma unroll
    for (int m = 0; m < 4; ++m) {
#pragma unroll
        for (int t = 0; t < NT; ++t) {
            int col = t * 16 + l16;
#pragma unroll
            for (int i = 0; i < 4; ++i) {
                int r = rowBase + m * 16 + quad * 4 + i;
                float v = acc[m][t][i];
                float nb = __shfl_xor(v, 1, 64);
                if (((lane & 1) == 0) && r < nrows)
                    Yb[(size_t)r * (FOUT / 2) + (col >> 1)] = pkf16(v, nb);
            }
        }
    }
}

// ---------------- MFMA GEMM layers 1-2 (bf16 X, single-bf16 W, 1 MFMA, 4 M-tiles) ----------------
// A already bf16-quantized -> split-W lo term is below the noise floor; drop it.
// Output packed FP16.

template <int FOUT>
__global__ __launch_bounds__(256) void gemm_bf16_kernel(const unsigned* __restrict__ Xb,
                                                        const unsigned short* __restrict__ whiT,
                                                        unsigned* __restrict__ Yb, int nrows) {
    constexpr int NT = FOUT / 16;
    __shared__ short shi[FOUT * LROW];

    for (int c = threadIdx.x; c < FOUT * 16; c += 256) {
        int n = c >> 4, r = c & 15;
        *(short8*)(shi + n * LROW + r * 8) = *(const short8*)(whiT + (size_t)n * 128 + r * 8);
    }
    __syncthreads();

    int lane = threadIdx.x & 63;
    int wave = threadIdx.x >> 6;
    int quad = lane >> 4;
    int l16 = lane & 15;
    int rowBase = blockIdx.x * 256 + wave * 64;

    f32x4 acc[4][NT];
#pragma unroll
    for (int m = 0; m < 4; ++m)
#pragma unroll
        for (int t = 0; t < NT; ++t) acc[m][t] = (f32x4){0.f, 0.f, 0.f, 0.f};

    const short* xs[4];
    bool ok[4];
#pragma unroll
    for (int m = 0; m < 4; ++m) {
        int arow = rowBase + m * 16 + l16;
        ok[m] = arow < nrows;
        xs[m] = (const short*)Xb + (size_t)arow * 128;
    }

#pragma unroll
    for (int k0 = 0; k0 < 128; k0 += 32) {
        short8 a[4];
#pragma unroll
        for (int m = 0; m < 4; ++m) {
            if (ok[m])
                a[m] = *(const short8*)(xs[m] + k0 + quad * 8);
            else
                a[m] = (short8){0, 0, 0, 0, 0, 0, 0, 0};
        }
#pragma unroll
        for (int t = 0; t < NT; ++t) {
            short8 b = *(const short8*)(shi + (t * 16 + l16) * LROW + k0 + quad * 8);
#pragma unroll
            for (int m = 0; m < 4; ++m)
                acc[m][t] = __builtin_amdgcn_mfma_f32_16x16x32_bf16(a[m], b, acc[m][t], 0, 0, 0);
        }
    }

#pragma unroll
    for (int m = 0; m < 4; ++m) {
#pragma unroll
        for (int t = 0; t < NT; ++t) {
            int col = t * 16 + l16;
#pragma unroll
            for (int i = 0; i < 4; ++i) {
                int r = rowBase + m * 16 + quad * 4 + i;
                float v = acc[m][t][i];
                float nb = __shfl_xor(v, 1, 64);
                if (((lane & 1) == 0) && r < nrows)
                    Yb[(size_t)r * (FOUT / 2) + (col >> 1)] = pkf16(v, nb);
            }
        }
    }
}

// ---------------- edge aggregation (F=128): fp16 gather + v_fma_mix ----------------
// per edge: 1 readlane (src -> SGPR base), 1 ds_bpermute (nrm, LDS pipe),
// 1 gather load, 2 v_fma_mix. No unpack VALU.

__global__ __launch_bounds__(256) void agg128_kernel(const unsigned* __restrict__ xlb,
                                                     const int* __restrict__ row_off,
                                                     const uint2* __restrict__ edges,
                                                     const float* __restrict__ dinv,
                                                     const float* __restrict__ bias,
                                                     unsigned* __restrict__ outb, int nnodes) {
    int wave = (blockIdx.x * blockDim.x + threadIdx.x) >> 6;
    int lane = threadIdx.x & 63;
    if (wave >= nnodes) return;
    int e0 = __builtin_amdgcn_readfirstlane(row_off[wave]);
    int e1 = __builtin_amdgcn_readfirstlane(row_off[wave + 1]);
    float ax = 0.f, ay = 0.f;
    int e = e0;
    int l16 = lane & 15;
    int nfull = (e1 - e0) >> 4;
    for (int r = 0; r < nfull; ++r, e += 16) {
        uint2 edv = edges[e + l16];
        unsigned pk[16];
        float nw[16];
#pragma unroll
        for (int j = 0; j < 16; ++j) {
            int sx = __builtin_amdgcn_readlane((int)edv.x, j);
            nw[j] = __uint_as_float((unsigned)__builtin_amdgcn_ds_bpermute(j * 4, (int)edv.y));
            pk[j] = xlb[(size_t)(unsigned)sx * 64 + lane];
        }
#pragma unroll
        for (int j = 0; j < 16; ++j) fmix2(ax, ay, pk[j], nw[j]);
    }
    if (e < e1) {  // masked tail round: zero nrm in-register before broadcast
        int idx = e + l16;
        uint2 edv = edges[idx < e1 ? idx : e1 - 1];
        if (idx >= e1) edv.y = 0u;
        unsigned pk[16];
        float nw[16];
#pragma unroll
        for (int j = 0; j < 16; ++j) {
            int sx = __builtin_amdgcn_readlane((int)edv.x, j);
            nw[j] = __uint_as_float((unsigned)__builtin_amdgcn_ds_bpermute(j * 4, (int)edv.y));
            pk[j] = xlb[(size_t)(unsigned)sx * 64 + lane];
        }
#pragma unroll
        for (int j = 0; j < 16; ++j) fmix2(ax, ay, pk[j], nw[j]);
    }
    float di = dinv[wave];
    float2 pi = f16unpack(xlb[(size_t)wave * 64 + lane]);
    float2 bb = *(const float2*)(bias + lane * 2);
    outb[(size_t)wave * 64 + lane] =
        bf16pair(gelu_f(ax + di * pi.x + bb.x), gelu_f(ay + di * pi.y + bb.y));
}

// ---------------- edge aggregation (F=64): node per half-wave, bpermute broadcast ----------------

__global__ __launch_bounds__(256) void agg64_kernel(const unsigned* __restrict__ xlb,
                                                    const int* __restrict__ row_off,
                                                    const uint2* __restrict__ edges,
                                                    const float* __restrict__ dinv,
                                                    const float* __restrict__ bias,
                                                    unsigned* __restrict__ outb, int nnodes) {
    int wave = (blockIdx.x * blockDim.x + threadIdx.x) >> 6;
    int lane = threadIdx.x & 63;
    int sub = lane >> 5;
    int sl = lane & 31;
    int node = wave * 2 + sub;
    bool nv = node < nnodes;
    int e0 = nv ? row_off[node] : 0;
    int e1 = nv ? row_off[node + 1] : 0;
    int rounds = (e1 - e0 + 15) >> 4;
    int ro = __shfl_xor(rounds, 32, 64);
    int maxr = rounds > ro ? rounds : ro;
    float ax = 0.f, ay = 0.f;
    int bidx = (lane & 32) << 2;  // bpermute byte base of this half's record lanes
    for (int r = 0; r < maxr; ++r) {
        int idx = e0 + (r << 4) + (lane & 15);
        int cl = idx < e1 ? idx : (e1 > e0 ? e1 - 1 : 0);
        uint2 edv = edges[cl];
        if (idx >= e1) edv.y = 0u;
        int sv[16];
        float nw[16];
#pragma unroll
        for (int j = 0; j < 16; ++j) {
            int bj = bidx + j * 4;
            sv[j] = __builtin_amdgcn_ds_bpermute(bj, (int)edv.x);
            nw[j] = __uint_as_float((unsigned)__builtin_amdgcn_ds_bpermute(bj, (int)edv.y));
        }
        unsigned pk[16];
#pragma unroll
        for (int j = 0; j < 16; ++j) pk[j] = xlb[(((unsigned)sv[j]) << 5) + (unsigned)sl];
#pragma unroll
        for (int j = 0; j < 16; ++j) fmix2(ax, ay, pk[j], nw[j]);
    }
    if (nv) {
        float di = dinv[node];
        float2 pi = f16unpack(xlb[(size_t)node * 32 + sl]);
        float2 bb = *(const float2*)(bias + sl * 2);
        outb[(size_t)node * 32 + sl] =
            bf16pair(gelu_f(ax + di * pi.x + bb.x), gelu_f(ay + di * pi.y + bb.y));
    }
}

// ---------------- mean pool (batch sorted, packed bf16 input) ----------------

#define POOL_CHUNK 64

__global__ __launch_bounds__(256) void pool_kernel(const unsigned* __restrict__ hb,
                                                   const int* __restrict__ batch,
                                                   float* __restrict__ psum,
                                                   float* __restrict__ pcnt, int nnodes) {
    int wave = (blockIdx.x * blockDim.x + threadIdx.x) >> 6;
    int lane = threadIdx.x & 63;
    int half = lane >> 5;
    int p = lane & 31;
    int n0 = wave * POOL_CHUNK + half * 32;
    if (n0 >= nnodes) return;
    int n1 = n0 + 32;
    if (n1 > nnodes) n1 = nnodes;

    int g_cur = batch[n0];
    float accx = 0.f, accy = 0.f;
    int cnt = 0;
    for (int node = n0; node < n1; ++node) {
        int g = batch[node];
        if (g != g_cur) {
            atomicAdd(&psum[g_cur * TDIM + 2 * p], accx);
            atomicAdd(&psum[g_cur * TDIM + 2 * p + 1], accy);
            if (p == 0) atomicAdd(&pcnt[g_cur], (float)cnt);
            accx = 0.f;
            accy = 0.f;
            cnt = 0;
            g_cur = g;
        }
        float2 f = bf16unpack(hb[(size_t)node * 32 + p]);
        accx += f.x;
        accy += f.y;
        ++cnt;
    }
    atomicAdd(&psum[g_cur * TDIM + 2 * p], accx);
    atomicAdd(&psum[g_cur * TDIM + 2 * p + 1], accy);
    if (p == 0) atomicAdd(&pcnt[g_cur], (float)cnt);
}

__global__ __launch_bounds__(256) void fin_kernel(const float* __restrict__ psum,
                                                  const float* __restrict__ pcnt,
                                                  float* __restrict__ out) {
    int i = blockIdx.x * blockDim.x + threadIdx.x;
    if (i < NGRAPH * TDIM) {
        float c = pcnt[i >> 6];
        out[i] = psum[i] / fmaxf(c, 1.0f);
    }
}

// ---------------- launch ----------------

extern "C" void kernel_launch(void* const* d_in, const int* in_sizes, int n_in,
                              void* d_out, int out_size, void* d_ws, size_t ws_size,
                              hipStream_t stream) {
    const float* x = (const float*)d_in[0];
    const int* ei = (const int*)d_in[1];
    const int* batch = (const int*)d_in[2];
    const float* W0 = (const float*)d_in[3];
    const float* b0 = (const float*)d_in[4];
    const float* W1 = (const float*)d_in[5];
    const float* b1 = (const float*)d_in[6];
    const float* W2 = (const float*)d_in[7];
    const float* b2 = (const float*)d_in[8];

    const int N = in_sizes[0] / F_IN;
    const int E = in_sizes[1] / 2;
    const int* src = ei;
    const int* dst = ei + E;
    const int NB = (N + 255) >> 8;

    char* w = (char*)d_ws;
    auto alloc = [&](size_t bytes) -> void* {
        void* p = (void*)w;
        w += (bytes + 255) & ~(size_t)255;
        return p;
    };
    float* isq = (float*)alloc((size_t)N * 4);
    float* dinv = (float*)alloc((size_t)N * 4);
    int* bucket_cnt = (int*)alloc((size_t)MAXNB * 4);
    int* bbase = (int*)alloc((size_t)MAXNB * 4);
    int* row_off = (int*)alloc((size_t)(N + 1) * 4);
    uint2* edges = (uint2*)alloc((size_t)E * 8);
    unsigned* tmp = (unsigned*)alloc((size_t)NB * CAP * 4);
    float* psum = (float*)alloc((size_t)NGRAPH * TDIM * 4);
    float* pcnt = (float*)alloc((size_t)NGRAPH * 4);
    unsigned* bufXb = (unsigned*)alloc((size_t)N * 64 * 4);
    unsigned* bufHb = (unsigned*)alloc((size_t)N * 64 * 4);
    unsigned short* whiT0 = (unsigned short*)alloc(128 * 128 * 2);
    unsigned short* wloT0 = (unsigned short*)alloc(128 * 128 * 2);
    unsigned short* whiT1 = (unsigned short*)alloc(128 * 128 * 2);
    unsigned short* wloT1 = (unsigned short*)alloc(128 * 128 * 2);
    unsigned short* whiT2 = (unsigned short*)alloc(64 * 128 * 2);
    unsigned short* wloT2 = (unsigned short*)alloc(64 * 128 * 2);

    zero_kernel<<<(NGRAPH * TDIM + 255) / 256, 256, 0, stream>>>(psum, pcnt, bucket_cnt);

    int cblocks = (E + BIN_CH - 1) / BIN_CH;
    binC_kernel<<<cblocks, 256, 0, stream>>>(src, dst, bucket_cnt, tmp, E, NB);
    scan_wconv_kernel<<<1 + (40960 + 255) / 256, 256, 0, stream>>>(
        bucket_cnt, bbase, row_off, NB, N, W0, W1, W2, whiT0, wloT0, whiT1, wloT1, whiT2,
        wloT2);
    binDcount_kernel<<<NB, 256, 0, stream>>>(tmp, bucket_cnt, bbase, row_off, isq, dinv, N);
    binDscatter_kernel<<<NB, 256, 0, stream>>>(tmp, bucket_cnt, row_off, isq, edges, N);

    int gblocks = (N + 255) / 256;
    int ablocks = (N * 64 + 255) / 256;
    int a64blocks = (((N + 1) / 2) * 64 + 255) / 256;

    // layer 0 (fp32 x input, split-W)
    gemm_f32_kernel<<<gblocks, 256, 0, stream>>>(x, whiT0, wloT0, bufXb, N);
    agg128_kernel<<<ablocks, 256, 0, stream>>>(bufXb, row_off, edges, dinv, b0, bufHb, N);
    // layer 1 (bf16 h input, single-W)
    gemm_bf16_kernel<128><<<gblocks, 256, 0, stream>>>(bufHb, whiT1, bufXb, N);
    agg128_kernel<<<ablocks, 256, 0, stream>>>(bufXb, row_off, edges, dinv, b1, bufHb, N);
    // layer 2 (Fout = 64, single-W)
    gemm_bf16_kernel<64><<<gblocks, 256, 0, stream>>>(bufHb, whiT2, bufXb, N);
    agg64_kernel<<<a64blocks, 256, 0, stream>>>(bufXb, row_off, edges, dinv, b2, bufHb, N);

    // pool
    int pwaves = (N + POOL_CHUNK - 1) / POOL_CHUNK;
    int pblocks = (pwaves * 64 + 255) / 256;
    pool_kernel<<<pblocks, 256, 0, stream>>>(bufHb, batch, psum, pcnt, N);
    fin_kernel<<<(NGRAPH * TDIM + 255) / 256, 256, 0, stream>>>(psum, pcnt, (float*)d_out);
}

// Round 3
// 381.463 us; speedup vs baseline: 1.1349x; 1.0140x over previous
//
#include <hip/hip_runtime.h>
#include <math.h>

#define F_IN 128
#define TDIM 64
#define NGRAPH 256

typedef __attribute__((ext_vector_type(8))) short short8;
typedef __attribute__((ext_vector_type(4))) float f32x4;
typedef __attribute__((ext_vector_type(2))) __fp16 fp16x2;

__device__ __forceinline__ float gelu_f(float x) {
    float x3 = x * x * x;
    return 0.5f * x * (1.0f + tanhf(0.7978845608028654f * (x + 0.044715f * x3)));
}

__device__ __forceinline__ unsigned short bf16_of(float x) {
    unsigned u = __float_as_uint(x);
    return (unsigned short)((u + 0x7fffu + ((u >> 16) & 1u)) >> 16);
}
__device__ __forceinline__ float f_of(unsigned short h) {
    return __uint_as_float(((unsigned)h) << 16);
}
__device__ __forceinline__ unsigned bf16pair(float a, float b) {
    return (unsigned)bf16_of(a) | ((unsigned)bf16_of(b) << 16);
}
__device__ __forceinline__ float2 bf16unpack(unsigned u) {
    float2 r;
    r.x = __uint_as_float(u << 16);
    r.y = __uint_as_float(u & 0xffff0000u);
    return r;
}

// fp16 pair pack/unpack (intermediate xl buffers are fp16)
__device__ __forceinline__ unsigned pkf16(float a, float b) {
    fp16x2 h = __builtin_amdgcn_cvt_pkrtz(a, b);
    return __builtin_bit_cast(unsigned, h);
}
__device__ __forceinline__ float2 f16unpack(unsigned u) {
    fp16x2 h = __builtin_bit_cast(fp16x2, u);
    float2 r;
    r.x = (float)h[0];
    r.y = (float)h[1];
    return r;
}

// acc += nw * f16lo(pk), acc2 += nw * f16hi(pk) -- single VALU op each, no unpack
__device__ __forceinline__ void fmix2(float& ax, float& ay, unsigned pk, float nw) {
    asm("v_fma_mix_f32 %0, %1, %2, %0 op_sel:[0,0,0] op_sel_hi:[1,0,0]"
        : "+v"(ax)
        : "v"(pk), "v"(nw));
    asm("v_fma_mix_f32 %0, %1, %2, %0 op_sel:[1,0,0] op_sel_hi:[1,0,0]"
        : "+v"(ay)
        : "v"(pk), "v"(nw));
}

// ---------------- edge build: fixed-stride bucket binning (packed records) ----------------

#define BIN_CH 4096
#define MAXNB 512
#define CAP 6144

__global__ __launch_bounds__(256) void zero_kernel(float* __restrict__ psum,
                                                   float* __restrict__ pcnt,
                                                   int* __restrict__ bucket_cnt) {
    int i = blockIdx.x * 256 + threadIdx.x;
    if (i < NGRAPH * TDIM) psum[i] = 0.f;
    if (i < NGRAPH) pcnt[i] = 0.f;
    if (i < MAXNB) bucket_cnt[i] = 0;
}

__global__ __launch_bounds__(256) void binC_kernel(const int* __restrict__ src,
                                                   const int* __restrict__ dst,
                                                   int* __restrict__ bucket_cnt,
                                                   unsigned* __restrict__ tmp, int E, int NB) {
    __shared__ int hist[MAXNB];
    __shared__ int hbase[MAXNB];
    __shared__ int hcur[MAXNB];
    int tid = threadIdx.x;
    int base = blockIdx.x * BIN_CH;
    int end = base + BIN_CH;
    if (end > E) end = E;
    for (int i = tid; i < NB; i += 256) hist[i] = 0;
    __syncthreads();
    for (int e = base + tid; e < end; e += 256) atomicAdd(&hist[dst[e] >> 8], 1);
    __syncthreads();
    for (int i = tid; i < NB; i += 256) {
        int c = hist[i];
        hbase[i] = (c > 0) ? atomicAdd(&bucket_cnt[i], c) : 0;
        hcur[i] = 0;
    }
    __syncthreads();
    for (int e = base + tid; e < end; e += 256) {
        int d = dst[e];
        int b = d >> 8;
        int p = atomicAdd(&hcur[b], 1);
        int slot = hbase[b] + p;
        if (slot < CAP)
            tmp[(size_t)b * CAP + slot] = (unsigned)src[e] | ((unsigned)(d & 255) << 24);
    }
}

// merged: block 0 = PARALLEL bucket scan; blocks >=1 = weight hi/lo split
__global__ __launch_bounds__(256) void scan_wconv_kernel(const int* __restrict__ bucket_cnt,
                                                         int* __restrict__ bbase,
                                                         int* __restrict__ row_off, int NB,
                                                         int N, const float* __restrict__ W0,
                                                         const float* __restrict__ W1,
                                                         const float* __restrict__ W2,
                                                         unsigned short* __restrict__ hi0,
                                                         unsigned short* __restrict__ lo0,
                                                         unsigned short* __restrict__ hi1,
                                                         unsigned short* __restrict__ lo1,
                                                         unsigned short* __restrict__ hi2,
                                                         unsigned short* __restrict__ lo2) {
    if (blockIdx.x == 0) {
        // parallel exclusive scan over NB (<= MAXNB = 512) clipped bucket counts
        __shared__ int sh[256];
        int tid = threadIdx.x;
        int i0 = tid * 2;
        int v0 = 0, v1 = 0;
        if (i0 < NB) {
            v0 = bucket_cnt[i0];
            v0 = v0 < CAP ? v0 : CAP;
        }
        if (i0 + 1 < NB) {
            v1 = bucket_cnt[i0 + 1];
            v1 = v1 < CAP ? v1 : CAP;
        }
        int s = v0 + v1;
        sh[tid] = s;
        __syncthreads();
        for (int off = 1; off < 256; off <<= 1) {
            int x = (tid >= off) ? sh[tid - off] : 0;
            __syncthreads();
            sh[tid] += x;
            __syncthreads();
        }
        int excl = sh[tid] - s;
        if (i0 < NB) bbase[i0] = excl;
        if (i0 + 1 < NB) bbase[i0 + 1] = excl + v0;
        if (tid == 255) row_off[N] = sh[255];
        return;
    }
    int idx = (blockIdx.x - 1) * 256 + threadIdx.x;
    const float* W;
    unsigned short *whi, *wlo;
    int local, FOUT;
    if (idx < 16384) {
        W = W0; whi = hi0; wlo = lo0; local = idx; FOUT = 128;
    } else if (idx < 32768) {
        W = W1; whi = hi1; wlo = lo1; local = idx - 16384; FOUT = 128;
    } else if (idx < 40960) {
        W = W2; whi = hi2; wlo = lo2; local = idx - 32768; FOUT = 64;
    } else {
        return;
    }
    int k = local / FOUT;
    int n = local % FOUT;
    float w = W[local];
    unsigned short h = bf16_of(w);
    whi[(size_t)n * 128 + k] = h;
    wlo[(size_t)n * 128 + k] = bf16_of(w - f_of(h));
}

__global__ __launch_bounds__(256) void binDcount_kernel(const unsigned* __restrict__ tmp,
                                                        const int* __restrict__ bucket_cnt,
                                                        const int* __restrict__ bbase,
                                                        int* __restrict__ row_off,
                                                        float* __restrict__ isq,
                                                        float* __restrict__ dinv, int N) {
    __shared__ int lcnt[256];
    __shared__ int sh[256];
    int b = blockIdx.x;
    int tid = threadIdx.x;
    int cntb = bucket_cnt[b];
    if (cntb > CAP) cntb = CAP;
    lcnt[tid] = 0;
    __syncthreads();
    const unsigned* tb = tmp + (size_t)b * CAP;
    for (int e = tid; e < cntb; e += 256) atomicAdd(&lcnt[tb[e] >> 24], 1);
    __syncthreads();
    int own = lcnt[tid];
    sh[tid] = own;
    __syncthreads();
    for (int off = 1; off < 256; off <<= 1) {
        int x = (tid >= off) ? sh[tid - off] : 0;
        __syncthreads();
        sh[tid] += x;
        __syncthreads();
    }
    int excl = sh[tid] - own;
    int node = (b << 8) + tid;
    if (node < N) {
        row_off[node] = bbase[b] + excl;
        float d = (float)own + 1.0f;
        isq[node] = rsqrtf(d);
        dinv[node] = 1.0f / d;
    }
}

__global__ __launch_bounds__(256) void binDscatter_kernel(const unsigned* __restrict__ tmp,
                                                          const int* __restrict__ bucket_cnt,
                                                          const int* __restrict__ row_off,
                                                          const float* __restrict__ isq,
                                                          uint2* __restrict__ edges, int N) {
    __shared__ int lcur[256];
    __shared__ float lisq[256];
    int b = blockIdx.x;
    int node0 = b << 8;
    int tid = threadIdx.x;
    lcur[tid] = 0;
    int nd = node0 + tid;
    lisq[tid] = (nd < N) ? isq[nd] : 0.f;
    __syncthreads();
    int cntb = bucket_cnt[b];
    if (cntb > CAP) cntb = CAP;
    const unsigned* tb = tmp + (size_t)b * CAP;
    for (int e = tid; e < cntb; e += 256) {
        unsigned rec = tb[e];
        int dl = (int)(rec >> 24);
        unsigned s = rec & 0xFFFFFFu;
        int p = atomicAdd(&lcur[dl], 1);
        float nrm = isq[s] * lisq[dl];
        edges[(size_t)row_off[node0 + dl] + p] = make_uint2(s, __float_as_uint(nrm));
    }
}

// ---------------- MFMA GEMM layer0 (fp32 X, split-bf16 W, 3 MFMA, 4 M-tiles/wave) ----------------

#define LROW 136  // LDS row stride in shorts (272 B)

__global__ __launch_bounds__(256) void gemm_f32_kernel(const float* __restrict__ X,
                                                       const unsigned short* __restrict__ whiT,
                                                       const unsigned short* __restrict__ wloT,
                                                       unsigned* __restrict__ Yb, int nrows) {
    constexpr int FOUT = 128;
    constexpr int NT = FOUT / 16;
    __shared__ short lds[2 * FOUT * LROW];
    short* shi = lds;
    short* slo = lds + FOUT * LROW;

    for (int c = threadIdx.x; c < FOUT * 16; c += 256) {
        int n = c >> 4, r = c & 15;
        *(short8*)(shi + n * LROW + r * 8) = *(const short8*)(whiT + (size_t)n * 128 + r * 8);
        *(short8*)(slo + n * LROW + r * 8) = *(const short8*)(wloT + (size_t)n * 128 + r * 8);
    }
    __syncthreads();

    int lane = threadIdx.x & 63;
    int wave = threadIdx.x >> 6;
    int quad = lane >> 4;
    int l16 = lane & 15;
    int rowBase = blockIdx.x * 256 + wave * 64;

    f32x4 acc[4][NT];
#pragma unroll
    for (int m = 0; m < 4; ++m)
#pragma unroll
        for (int t = 0; t < NT; ++t) acc[m][t] = (f32x4){0.f, 0.f, 0.f, 0.f};

    const float* xr[4];
    bool ok[4];
#pragma unroll
    for (int m = 0; m < 4; ++m) {
        int arow = rowBase + m * 16 + l16;
        ok[m] = arow < nrows;
        xr[m] = X + (size_t)arow * 128;
    }

#pragma unroll
    for (int k0 = 0; k0 < 128; k0 += 32) {
        short8 ahi[4], alo[4];
#pragma unroll
        for (int m = 0; m < 4; ++m) {
            float xv[8];
            if (ok[m]) {
                float4 v0 = *(const float4*)(xr[m] + k0 + quad * 8);
                float4 v1 = *(const float4*)(xr[m] + k0 + quad * 8 + 4);
                xv[0] = v0.x; xv[1] = v0.y; xv[2] = v0.z; xv[3] = v0.w;
                xv[4] = v1.x; xv[5] = v1.y; xv[6] = v1.z; xv[7] = v1.w;
            } else {
#pragma unroll
                for (int j = 0; j < 8; ++j) xv[j] = 0.f;
            }
#pragma unroll
            for (int j = 0; j < 8; ++j) {
                unsigned short h = bf16_of(xv[j]);
                ahi[m][j] = (short)h;
                alo[m][j] = (short)bf16_of(xv[j] - f_of(h));
            }
        }
#pragma unroll
        for (int t = 0; t < NT; ++t) {
            int off = (t * 16 + l16) * LROW + k0 + quad * 8;
            short8 bhi = *(const short8*)(shi + off);
            short8 blo = *(const short8*)(slo + off);
#pragma unroll
            for (int m = 0; m < 4; ++m) {
                acc[m][t] = __builtin_amdgcn_mfma_f32_16x16x32_bf16(ahi[m], bhi, acc[m][t], 0, 0, 0);
                acc[m][t] = __builtin_amdgcn_mfma_f32_16x16x32_bf16(alo[m], bhi, acc[m][t], 0, 0, 0);
                acc[m][t] = __builtin_amdgcn_mfma_f32_16x16x32_bf16(ahi[m], blo, acc[m][t], 0, 0, 0);
            }
        }
    }

#pragma unroll
    for (int m = 0; m < 4; ++m) {
#pragma unroll
        for (int t = 0; t < NT; ++t) {
            int col = t * 16 + l16;
#pragma unroll
            for (int i = 0; i < 4; ++i) {
                int r = rowBase + m * 16 + quad * 4 + i;
                float v = acc[m][t][i];
                float nb = __shfl_xor(v, 1, 64);
                if (((lane & 1) == 0) && r < nrows)
                    Yb[(size_t)r * (FOUT / 2) + (col >> 1)] = pkf16(v, nb);
            }
        }
    }
}

// ---------------- MFMA GEMM layers 1-2 (bf16 X, single-bf16 W, 1 MFMA, 4 M-tiles) ----------------

template <int FOUT>
__global__ __launch_bounds__(256) void gemm_bf16_kernel(const unsigned* __restrict__ Xb,
                                                        const unsigned short* __restrict__ whiT,
                                                        unsigned* __restrict__ Yb, int nrows) {
    constexpr int NT = FOUT / 16;
    __shared__ short shi[FOUT * LROW];

    for (int c = threadIdx.x; c < FOUT * 16; c += 256) {
        int n = c >> 4, r = c & 15;
        *(short8*)(shi + n * LROW + r * 8) = *(const short8*)(whiT + (size_t)n * 128 + r * 8);
    }
    __syncthreads();

    int lane = threadIdx.x & 63;
    int wave = threadIdx.x >> 6;
    int quad = lane >> 4;
    int l16 = lane & 15;
    int rowBase = blockIdx.x * 256 + wave * 64;

    f32x4 acc[4][NT];
#pragma unroll
    for (int m = 0; m < 4; ++m)
#pragma unroll
        for (int t = 0; t < NT; ++t) acc[m][t] = (f32x4){0.f, 0.f, 0.f, 0.f};

    const short* xs[4];
    bool ok[4];
#pragma unroll
    for (int m = 0; m < 4; ++m) {
        int arow = rowBase + m * 16 + l16;
        ok[m] = arow < nrows;
        xs[m] = (const short*)Xb + (size_t)arow * 128;
    }

#pragma unroll
    for (int k0 = 0; k0 < 128; k0 += 32) {
        short8 a[4];
#pragma unroll
        for (int m = 0; m < 4; ++m) {
            if (ok[m])
                a[m] = *(const short8*)(xs[m] + k0 + quad * 8);
            else
                a[m] = (short8){0, 0, 0, 0, 0, 0, 0, 0};
        }
#pragma unroll
        for (int t = 0; t < NT; ++t) {
            short8 b = *(const short8*)(shi + (t * 16 + l16) * LROW + k0 + quad * 8);
#pragma unroll
            for (int m = 0; m < 4; ++m)
                acc[m][t] = __builtin_amdgcn_mfma_f32_16x16x32_bf16(a[m], b, acc[m][t], 0, 0, 0);
        }
    }

#pragma unroll
    for (int m = 0; m < 4; ++m) {
#pragma unroll
        for (int t = 0; t < NT; ++t) {
            int col = t * 16 + l16;
#pragma unroll
            for (int i = 0; i < 4; ++i) {
                int r = rowBase + m * 16 + quad * 4 + i;
                float v = acc[m][t][i];
                float nb = __shfl_xor(v, 1, 64);
                if (((lane & 1) == 0) && r < nrows)
                    Yb[(size_t)r * (FOUT / 2) + (col >> 1)] = pkf16(v, nb);
            }
        }
    }
}

// ---------------- edge aggregation (F=128): fp16 gather + v_fma_mix, forced-MLP ----------------
// sched_barrier(0) between gather-issue and consume keeps all 16 gathers in flight
// (at VGPR=24 the compiler had fused the loops and serialized the gathers).

__global__ __launch_bounds__(256) void agg128_kernel(const unsigned* __restrict__ xlb,
                                                     const int* __restrict__ row_off,
                                                     const uint2* __restrict__ edges,
                                                     const float* __restrict__ dinv,
                                                     const float* __restrict__ bias,
                                                     unsigned* __restrict__ outb, int nnodes) {
    int wave = (blockIdx.x * blockDim.x + threadIdx.x) >> 6;
    int lane = threadIdx.x & 63;
    if (wave >= nnodes) return;
    int e0 = __builtin_amdgcn_readfirstlane(row_off[wave]);
    int e1 = __builtin_amdgcn_readfirstlane(row_off[wave + 1]);
    float ax = 0.f, ay = 0.f;
    int e = e0;
    int l16 = lane & 15;
    int nfull = (e1 - e0) >> 4;
    for (int r = 0; r < nfull; ++r, e += 16) {
        uint2 edv = edges[e + l16];
        unsigned pk[16];
        float nw[16];
#pragma unroll
        for (int j = 0; j < 16; ++j) {
            int sx = __builtin_amdgcn_readlane((int)edv.x, j);
            nw[j] = __uint_as_float((unsigned)__builtin_amdgcn_ds_bpermute(j * 4, (int)edv.y));
            pk[j] = xlb[(size_t)(unsigned)sx * 64 + lane];
        }
        __builtin_amdgcn_sched_barrier(0);  // all 16 gathers issued before first consume
#pragma unroll
        for (int j = 0; j < 16; ++j) fmix2(ax, ay, pk[j], nw[j]);
    }
    if (e < e1) {  // masked tail round: zero nrm in-register before broadcast
        int idx = e + l16;
        uint2 edv = edges[idx < e1 ? idx : e1 - 1];
        if (idx >= e1) edv.y = 0u;
        unsigned pk[16];
        float nw[16];
#pragma unroll
        for (int j = 0; j < 16; ++j) {
            int sx = __builtin_amdgcn_readlane((int)edv.x, j);
            nw[j] = __uint_as_float((unsigned)__builtin_amdgcn_ds_bpermute(j * 4, (int)edv.y));
            pk[j] = xlb[(size_t)(unsigned)sx * 64 + lane];
        }
        __builtin_amdgcn_sched_barrier(0);
#pragma unroll
        for (int j = 0; j < 16; ++j) fmix2(ax, ay, pk[j], nw[j]);
    }
    float di = dinv[wave];
    float2 pi = f16unpack(xlb[(size_t)wave * 64 + lane]);
    float2 bb = *(const float2*)(bias + lane * 2);
    outb[(size_t)wave * 64 + lane] =
        bf16pair(gelu_f(ax + di * pi.x + bb.x), gelu_f(ay + di * pi.y + bb.y));
}

// ---------------- edge aggregation (F=64): node per half-wave, forced-MLP ----------------

__global__ __launch_bounds__(256) void agg64_kernel(const unsigned* __restrict__ xlb,
                                                    const int* __restrict__ row_off,
                                                    const uint2* __restrict__ edges,
                                                    const float* __restrict__ dinv,
                                                    const float* __restrict__ bias,
                                                    unsigned* __restrict__ outb, int nnodes) {
    int wave = (blockIdx.x * blockDim.x + threadIdx.x) >> 6;
    int lane = threadIdx.x & 63;
    int sub = lane >> 5;
    int sl = lane & 31;
    int node = wave * 2 + sub;
    bool nv = node < nnodes;
    int e0 = nv ? row_off[node] : 0;
    int e1 = nv ? row_off[node + 1] : 0;
    int rounds = (e1 - e0 + 15) >> 4;
    int ro = __shfl_xor(rounds, 32, 64);
    int maxr = rounds > ro ? rounds : ro;
    float ax = 0.f, ay = 0.f;
    int bidx = (lane & 32) << 2;  // bpermute byte base of this half's record lanes
    for (int r = 0; r < maxr; ++r) {
        int idx = e0 + (r << 4) + (lane & 15);
        int cl = idx < e1 ? idx : (e1 > e0 ? e1 - 1 : 0);
        uint2 edv = edges[cl];
        if (idx >= e1) edv.y = 0u;
        int sv[16];
        float nw[16];
#pragma unroll
        for (int j = 0; j < 16; ++j) {
            int bj = bidx + j * 4;
            sv[j] = __builtin_amdgcn_ds_bpermute(bj, (int)edv.x);
            nw[j] = __uint_as_float((unsigned)__builtin_amdgcn_ds_bpermute(bj, (int)edv.y));
        }
        unsigned pk[16];
#pragma unroll
        for (int j = 0; j < 16; ++j) pk[j] = xlb[(((unsigned)sv[j]) << 5) + (unsigned)sl];
        __builtin_amdgcn_sched_barrier(0);  // all 16 gathers in flight before consume
#pragma unroll
        for (int j = 0; j < 16; ++j) fmix2(ax, ay, pk[j], nw[j]);
    }
    if (nv) {
        float di = dinv[node];
        float2 pi = f16unpack(xlb[(size_t)node * 32 + sl]);
        float2 bb = *(const float2*)(bias + sl * 2);
        outb[(size_t)node * 32 + sl] =
            bf16pair(gelu_f(ax + di * pi.x + bb.x), gelu_f(ay + di * pi.y + bb.y));
    }
}

// ---------------- mean pool (batch sorted, packed bf16 input) ----------------

#define POOL_CHUNK 64

__global__ __launch_bounds__(256) void pool_kernel(const unsigned* __restrict__ hb,
                                                   const int* __restrict__ batch,
                                                   float* __restrict__ psum,
                                                   float* __restrict__ pcnt, int nnodes) {
    int wave = (blockIdx.x * blockDim.x + threadIdx.x) >> 6;
    int lane = threadIdx.x & 63;
    int half = lane >> 5;
    int p = lane & 31;
    int n0 = wave * POOL_CHUNK + half * 32;
    if (n0 >= nnodes) return;
    int n1 = n0 + 32;
    if (n1 > nnodes) n1 = nnodes;

    int g_cur = batch[n0];
    float accx = 0.f, accy = 0.f;
    int cnt = 0;
    for (int node = n0; node < n1; ++node) {
        int g = batch[node];
        if (g != g_cur) {
            atomicAdd(&psum[g_cur * TDIM + 2 * p], accx);
            atomicAdd(&psum[g_cur * TDIM + 2 * p + 1], accy);
            if (p == 0) atomicAdd(&pcnt[g_cur], (float)cnt);
            accx = 0.f;
            accy = 0.f;
            cnt = 0;
            g_cur = g;
        }
        float2 f = bf16unpack(hb[(size_t)node * 32 + p]);
        accx += f.x;
        accy += f.y;
        ++cnt;
    }
    atomicAdd(&psum[g_cur * TDIM + 2 * p], accx);
    atomicAdd(&psum[g_cur * TDIM + 2 * p + 1], accy);
    if (p == 0) atomicAdd(&pcnt[g_cur], (float)cnt);
}

__global__ __launch_bounds__(256) void fin_kernel(const float* __restrict__ psum,
                                                  const float* __restrict__ pcnt,
                                                  float* __restrict__ out) {
    int i = blockIdx.x * blockDim.x + threadIdx.x;
    if (i < NGRAPH * TDIM) {
        float c = pcnt[i >> 6];
        out[i] = psum[i] / fmaxf(c, 1.0f);
    }
}

// ---------------- launch ----------------

extern "C" void kernel_launch(void* const* d_in, const int* in_sizes, int n_in,
                              void* d_out, int out_size, void* d_ws, size_t ws_size,
                              hipStream_t stream) {
    const float* x = (const float*)d_in[0];
    const int* ei = (const int*)d_in[1];
    const int* batch = (const int*)d_in[2];
    const float* W0 = (const float*)d_in[3];
    const float* b0 = (const float*)d_in[4];
    const float* W1 = (const float*)d_in[5];
    const float* b1 = (const float*)d_in[6];
    const float* W2 = (const float*)d_in[7];
    const float* b2 = (const float*)d_in[8];

    const int N = in_sizes[0] / F_IN;
    const int E = in_sizes[1] / 2;
    const int* src = ei;
    const int* dst = ei + E;
    const int NB = (N + 255) >> 8;

    char* w = (char*)d_ws;
    auto alloc = [&](size_t bytes) -> void* {
        void* p = (void*)w;
        w += (bytes + 255) & ~(size_t)255;
        return p;
    };
    float* isq = (float*)alloc((size_t)N * 4);
    float* dinv = (float*)alloc((size_t)N * 4);
    int* bucket_cnt = (int*)alloc((size_t)MAXNB * 4);
    int* bbase = (int*)alloc((size_t)MAXNB * 4);
    int* row_off = (int*)alloc((size_t)(N + 1) * 4);
    uint2* edges = (uint2*)alloc((size_t)E * 8);
    unsigned* tmp = (unsigned*)alloc((size_t)NB * CAP * 4);
    float* psum = (float*)alloc((size_t)NGRAPH * TDIM * 4);
    float* pcnt = (float*)alloc((size_t)NGRAPH * 4);
    unsigned* bufXb = (unsigned*)alloc((size_t)N * 64 * 4);
    unsigned* bufHb = (unsigned*)alloc((size_t)N * 64 * 4);
    unsigned short* whiT0 = (unsigned short*)alloc(128 * 128 * 2);
    unsigned short* wloT0 = (unsigned short*)alloc(128 * 128 * 2);
    unsigned short* whiT1 = (unsigned short*)alloc(128 * 128 * 2);
    unsigned short* wloT1 = (unsigned short*)alloc(128 * 128 * 2);
    unsigned short* whiT2 = (unsigned short*)alloc(64 * 128 * 2);
    unsigned short* wloT2 = (unsigned short*)alloc(64 * 128 * 2);

    zero_kernel<<<(NGRAPH * TDIM + 255) / 256, 256, 0, stream>>>(psum, pcnt, bucket_cnt);

    int cblocks = (E + BIN_CH - 1) / BIN_CH;
    binC_kernel<<<cblocks, 256, 0, stream>>>(src, dst, bucket_cnt, tmp, E, NB);
    scan_wconv_kernel<<<1 + (40960 + 255) / 256, 256, 0, stream>>>(
        bucket_cnt, bbase, row_off, NB, N, W0, W1, W2, whiT0, wloT0, whiT1, wloT1, whiT2,
        wloT2);
    binDcount_kernel<<<NB, 256, 0, stream>>>(tmp, bucket_cnt, bbase, row_off, isq, dinv, N);
    binDscatter_kernel<<<NB, 256, 0, stream>>>(tmp, bucket_cnt, row_off, isq, edges, N);

    int gblocks = (N + 255) / 256;
    int ablocks = (N * 64 + 255) / 256;
    int a64blocks = (((N + 1) / 2) * 64 + 255) / 256;

    // layer 0 (fp32 x input, split-W)
    gemm_f32_kernel<<<gblocks, 256, 0, stream>>>(x, whiT0, wloT0, bufXb, N);
    agg128_kernel<<<ablocks, 256, 0, stream>>>(bufXb, row_off, edges, dinv, b0, bufHb, N);
    // layer 1 (bf16 h input, single-W)
    gemm_bf16_kernel<128><<<gblocks, 256, 0, stream>>>(bufHb, whiT1, bufXb, N);
    agg128_kernel<<<ablocks, 256, 0, stream>>>(bufXb, row_off, edges, dinv, b1, bufHb, N);
    // layer 2 (Fout = 64, single-W)
    gemm_bf16_kernel<64><<<gblocks, 256, 0, stream>>>(bufHb, whiT2, bufXb, N);
    agg64_kernel<<<a64blocks, 256, 0, stream>>>(bufXb, row_off, edges, dinv, b2, bufHb, N);

    // pool
    int pwaves = (N + POOL_CHUNK - 1) / POOL_CHUNK;
    int pblocks = (pwaves * 64 + 255) / 256;
    pool_kernel<<<pblocks, 256, 0, stream>>>(bufHb, batch, psum, pcnt, N);
    fin_kernel<<<(NGRAPH * TDIM + 255) / 256, 256, 0, stream>>>(psum, pcnt, (float*)d_out);
}